// Round 1
// baseline (125.440 us; speedup 1.0000x reference)
//
#include <hip/hip_runtime.h>

#define TC 256
#define DEMB 384
#define WIN 96
#define TTILE 32
#define LOG_SQRT_2PI 0.9189385332046727f

__global__ __launch_bounds__(256) void gauss_embed_kernel(
    const int* __restrict__ text,    // [32, 256]
    const int* __restrict__ durs,    // [32, 256]
    const float* __restrict__ embed, // [100, 384]
    float* __restrict__ out,         // [32, Tt, 384]
    int Tt)
{
    const int b   = blockIdx.y;
    const int t0  = blockIdx.x * TTILE;
    const int tid = threadIdx.x;

    __shared__ float s_scan[TC];
    __shared__ float s_wc[WIN], s_wis[WIN], s_wA[WIN];
    __shared__ int   s_wtx[WIN];
    __shared__ __align__(16) float s_w[WIN][TTILE];
    __shared__ float s_invS[TTILE];
    __shared__ int   s_j0, s_totdur;

    // ---- inclusive scan of durations (exact in fp32: values <= 2048) ----
    s_scan[tid] = (float)durs[b * TC + tid];
    if (tid == 0) s_j0 = TC - 1;
    __syncthreads();
    for (int ofs = 1; ofs < TC; ofs <<= 1) {
        float v = (tid >= ofs) ? s_scan[tid - ofs] : 0.0f;
        __syncthreads();
        s_scan[tid] += v;
        __syncthreads();
    }

    // ---- find char covering frame t0; total duration ----
    {
        int en = (int)s_scan[tid];
        int st = tid ? (int)s_scan[tid - 1] : 0;
        if (t0 >= st && t0 < en) s_j0 = tid;       // unique (durs >= 1)
        if (tid == 0) s_totdur = (int)s_scan[TC - 1];
    }
    __syncthreads();

    int base = s_j0 - 31;
    base = base < 0 ? 0 : (base > TC - WIN ? TC - WIN : base);
    const int totdur = s_totdur;

    // ---- stage window metadata ----
    if (tid < WIN) {
        int j = base + tid;
        float endf   = s_scan[j];
        float startf = j ? s_scan[j - 1] : 0.0f;
        float dur = endf - startf;
        float sig = dur * 0.5f + 1e-6f;            // dur/SIGMA_C + EPS
        s_wc[tid]  = endf - dur * 0.5f;            // center
        s_wis[tid] = 1.0f / sig;
        s_wA[tid]  = -logf(sig) - LOG_SQRT_2PI;
        s_wtx[tid] = text[b * TC + j];
    }
    __syncthreads();

    // ---- phase 1: gaussian weights w[c][t] ----
    for (int i = tid; i < WIN * TTILE; i += 256) {
        int c  = i >> 5;
        int tt = i & 31;
        float tf = (float)(t0 + tt) + 0.5f;
        float z  = (tf - s_wc[c]) * s_wis[c];
        float p  = fmaf(-0.5f * z, z, s_wA[c]);
        s_w[c][tt] = expf(p);
    }
    __syncthreads();

    // ---- per-t normalizers ----
    if (tid < TTILE) {
        float s = 0.0f;
        for (int c = 0; c < WIN; ++c) s += s_w[c][tid];
        s_invS[tid] = 1.0f / (s + 1e-6f);
    }
    __syncthreads();

    // ---- phase 2: weighted embedding sum ----
    const int wv   = tid >> 6;   // wave id: owns t-local [8wv, 8wv+8)
    const int lane = tid & 63;   // owns d = {2*lane, 2*lane+1} + 128*k, k=0..2
    const int tb   = wv * 8;

    float2 acc[8][3];
#pragma unroll
    for (int i = 0; i < 8; ++i)
#pragma unroll
        for (int k = 0; k < 3; ++k) acc[i][k] = make_float2(0.0f, 0.0f);

    for (int c = 0; c < WIN; ++c) {
        int idx = __builtin_amdgcn_readfirstlane(s_wtx[c]);
        const float2* erow = (const float2*)(embed + (size_t)idx * DEMB);
        float2 e0 = erow[lane];
        float2 e1 = erow[lane + 64];
        float2 e2 = erow[lane + 128];
        const float4 wa = *(const float4*)(&s_w[c][tb]);
        const float4 wb = *(const float4*)(&s_w[c][tb + 4]);
        float wl[8] = {wa.x, wa.y, wa.z, wa.w, wb.x, wb.y, wb.z, wb.w};
#pragma unroll
        for (int tt = 0; tt < 8; ++tt) {
            float wgt = wl[tt];
            acc[tt][0].x = fmaf(wgt, e0.x, acc[tt][0].x);
            acc[tt][0].y = fmaf(wgt, e0.y, acc[tt][0].y);
            acc[tt][1].x = fmaf(wgt, e1.x, acc[tt][1].x);
            acc[tt][1].y = fmaf(wgt, e1.y, acc[tt][1].y);
            acc[tt][2].x = fmaf(wgt, e2.x, acc[tt][2].x);
            acc[tt][2].y = fmaf(wgt, e2.y, acc[tt][2].y);
        }
    }

    // pad row (t >= total_dur) collapses to embed[PAD=0]
    const float2* prow = (const float2*)embed;
    float2 p0 = prow[lane], p1 = prow[lane + 64], p2 = prow[lane + 128];

#pragma unroll
    for (int tt = 0; tt < 8; ++tt) {
        int t = t0 + tb + tt;
        if (t >= Tt) continue;
        float2 o0, o1, o2;
        if (t >= totdur) {
            o0 = p0; o1 = p1; o2 = p2;
        } else {
            float s = s_invS[tb + tt];
            o0 = make_float2(acc[tt][0].x * s, acc[tt][0].y * s);
            o1 = make_float2(acc[tt][1].x * s, acc[tt][1].y * s);
            o2 = make_float2(acc[tt][2].x * s, acc[tt][2].y * s);
        }
        float2* orow = (float2*)(out + (size_t)(b * Tt + t) * DEMB);
        orow[lane]       = o0;
        orow[lane + 64]  = o1;
        orow[lane + 128] = o2;
    }
}

extern "C" void kernel_launch(void* const* d_in, const int* in_sizes, int n_in,
                              void* d_out, int out_size, void* d_ws, size_t ws_size,
                              hipStream_t stream) {
    const int*   text  = (const int*)d_in[0];
    const int*   durs  = (const int*)d_in[1];
    const float* embed = (const float*)d_in[2];
    float* out = (float*)d_out;

    const int B = 32;
    const int Tt = out_size / (B * DEMB);   // out = [B, Tt, 384]

    dim3 grid((Tt + TTILE - 1) / TTILE, B);
    gauss_embed_kernel<<<grid, 256, 0, stream>>>(text, durs, embed, out, Tt);
}

// Round 2
// 118.077 us; speedup vs baseline: 1.0624x; 1.0624x over previous
//
#include <hip/hip_runtime.h>

#define TC 256
#define DEMB 384
#define WIN 96
#define TTILE 32
#define NTHR 128
#define LOG_SQRT_2PI 0.9189385332046727f

__global__ __launch_bounds__(NTHR, 2) void gauss_embed_kernel(
    const int* __restrict__ text,    // [32, 256]
    const int* __restrict__ durs,    // [32, 256]
    const float* __restrict__ embed, // [100, 384]
    float* __restrict__ out,         // [32, Tt, 384]
    int Tt)
{
    const int b   = blockIdx.y;
    const int t0  = blockIdx.x * TTILE;
    const int tid = threadIdx.x;     // 0..127

    __shared__ float s_scan[TC];
    __shared__ float s_pair[NTHR];
    __shared__ float s_wc[WIN], s_wis[WIN], s_wA[WIN];
    __shared__ int   s_wtx[WIN];
    __shared__ __align__(16) float s_w[WIN][TTILE];
    __shared__ float s_invS[TTILE];
    __shared__ int   s_j0, s_totdur;

    // ---- inclusive scan of durations via pair-sums (exact in fp32) ----
    const int dA = durs[b * TC + 2 * tid];
    const int dB = durs[b * TC + 2 * tid + 1];
    s_pair[tid] = (float)(dA + dB);
    if (tid == 0) s_j0 = TC - 1;
    __syncthreads();
    for (int ofs = 1; ofs < NTHR; ofs <<= 1) {
        float v = (tid >= ofs) ? s_pair[tid - ofs] : 0.0f;
        __syncthreads();
        s_pair[tid] += v;
        __syncthreads();
    }
    {
        float P = s_pair[tid];               // sum durs[0 .. 2*tid+1]
        s_scan[2 * tid + 1] = P;
        s_scan[2 * tid]     = P - (float)dB;
    }
    __syncthreads();

    // ---- find char covering frame t0; total duration ----
    {
#pragma unroll
        for (int k = 0; k < 2; ++k) {
            int j  = 2 * tid + k;
            int en = (int)s_scan[j];
            int st = j ? (int)s_scan[j - 1] : 0;
            if (t0 >= st && t0 < en) s_j0 = j;   // unique (durs >= 1)
        }
        if (tid == 0) s_totdur = (int)s_scan[TC - 1];
    }
    __syncthreads();

    int base = s_j0 - 31;
    base = base < 0 ? 0 : (base > TC - WIN ? TC - WIN : base);
    const int totdur = s_totdur;

    // ---- stage window metadata ----
    if (tid < WIN) {
        int j = base + tid;
        float endf   = s_scan[j];
        float startf = j ? s_scan[j - 1] : 0.0f;
        float dur = endf - startf;
        float sig = dur * 0.5f + 1e-6f;          // dur/SIGMA_C + EPS
        s_wc[tid]  = endf - dur * 0.5f;          // center
        s_wis[tid] = 1.0f / sig;
        s_wA[tid]  = -logf(sig) - LOG_SQRT_2PI;
        s_wtx[tid] = text[b * TC + j];
    }
    __syncthreads();

    // ---- phase 1: gaussian weights w[c][t] ----
    for (int i = tid; i < WIN * TTILE; i += NTHR) {
        int c  = i >> 5;
        int tt = i & 31;
        float tf = (float)(t0 + tt) + 0.5f;
        float z  = (tf - s_wc[c]) * s_wis[c];
        float p  = fmaf(-0.5f * z, z, s_wA[c]);
        s_w[c][tt] = expf(p);
    }
    __syncthreads();

    // ---- per-t normalizers ----
    if (tid < TTILE) {
        float s = 0.0f;
        for (int c = 0; c < WIN; ++c) s += s_w[c][tid];
        s_invS[tid] = 1.0f / (s + 1e-6f);
    }
    __syncthreads();

    // ---- phase 2: weighted embedding sum; wave owns 16 t's ----
    const int wv   = tid >> 6;   // 0 or 1: t-local range [16wv, 16wv+16)
    const int lane = tid & 63;   // d = {2*lane, 2*lane+1} + 128*k, k=0..2
    const int tb   = wv * 16;

    float2 acc[16][3];
#pragma unroll
    for (int i = 0; i < 16; ++i)
#pragma unroll
        for (int k = 0; k < 3; ++k) acc[i][k] = make_float2(0.0f, 0.0f);

#pragma unroll 2
    for (int c = 0; c < WIN; ++c) {
        int idx = __builtin_amdgcn_readfirstlane(s_wtx[c]);
        const float2* erow = (const float2*)(embed + (size_t)idx * DEMB);
        float2 e0 = erow[lane];
        float2 e1 = erow[lane + 64];
        float2 e2 = erow[lane + 128];
        const float4 w0 = *(const float4*)(&s_w[c][tb]);
        const float4 w1 = *(const float4*)(&s_w[c][tb + 4]);
        const float4 w2 = *(const float4*)(&s_w[c][tb + 8]);
        const float4 w3 = *(const float4*)(&s_w[c][tb + 12]);
        float wl[16] = {w0.x, w0.y, w0.z, w0.w, w1.x, w1.y, w1.z, w1.w,
                        w2.x, w2.y, w2.z, w2.w, w3.x, w3.y, w3.z, w3.w};
#pragma unroll
        for (int tt = 0; tt < 16; ++tt) {
            float wgt = wl[tt];
            acc[tt][0].x = fmaf(wgt, e0.x, acc[tt][0].x);
            acc[tt][0].y = fmaf(wgt, e0.y, acc[tt][0].y);
            acc[tt][1].x = fmaf(wgt, e1.x, acc[tt][1].x);
            acc[tt][1].y = fmaf(wgt, e1.y, acc[tt][1].y);
            acc[tt][2].x = fmaf(wgt, e2.x, acc[tt][2].x);
            acc[tt][2].y = fmaf(wgt, e2.y, acc[tt][2].y);
        }
    }

    // pad row (t >= total_dur) collapses to embed[PAD=0]
    const float2* prow = (const float2*)embed;
    float2 p0 = prow[lane], p1 = prow[lane + 64], p2 = prow[lane + 128];

#pragma unroll
    for (int tt = 0; tt < 16; ++tt) {
        int t = t0 + tb + tt;
        if (t >= Tt) continue;
        float2 o0, o1, o2;
        if (t >= totdur) {
            o0 = p0; o1 = p1; o2 = p2;
        } else {
            float s = s_invS[tb + tt];
            o0 = make_float2(acc[tt][0].x * s, acc[tt][0].y * s);
            o1 = make_float2(acc[tt][1].x * s, acc[tt][1].y * s);
            o2 = make_float2(acc[tt][2].x * s, acc[tt][2].y * s);
        }
        float2* orow = (float2*)(out + (size_t)(b * Tt + t) * DEMB);
        orow[lane]       = o0;
        orow[lane + 64]  = o1;
        orow[lane + 128] = o2;
    }
}

extern "C" void kernel_launch(void* const* d_in, const int* in_sizes, int n_in,
                              void* d_out, int out_size, void* d_ws, size_t ws_size,
                              hipStream_t stream) {
    const int*   text  = (const int*)d_in[0];
    const int*   durs  = (const int*)d_in[1];
    const float* embed = (const float*)d_in[2];
    float* out = (float*)d_out;

    const int B = 32;
    const int Tt = out_size / (B * DEMB);   // out = [B, Tt, 384]

    dim3 grid((Tt + TTILE - 1) / TTILE, B);
    gauss_embed_kernel<<<grid, NTHR, 0, stream>>>(text, durs, embed, out, Tt);
}

// Round 3
// 105.968 us; speedup vs baseline: 1.1838x; 1.1143x over previous
//
#include <hip/hip_runtime.h>

#define TC 256
#define DEMB 384
#define VOC 100
#define WIN 96
#define TTILE 32
#define WPS 104      // W' LDS row stride in bf16 elems (16B-aligned rows)
#define LOG_SQRT_2PI 0.9189385332046727f

typedef short v8s __attribute__((ext_vector_type(8)));
typedef float v4f __attribute__((ext_vector_type(4)));

__device__ __forceinline__ unsigned short f32_to_bf16_rne(float f) {
    union { float f; unsigned int u; } x; x.f = f;
    unsigned int u = x.u;
    return (unsigned short)((u + 0x7FFFu + ((u >> 16) & 1u)) >> 16);
}

// One-time: embT[n][v] = bf16(embed[v][n]);  [384][100] bf16 in d_ws
__global__ __launch_bounds__(256) void embed_transpose_kernel(
    const float* __restrict__ embed, unsigned short* __restrict__ embT)
{
    int i = blockIdx.x * 256 + threadIdx.x;
    if (i >= DEMB * VOC) return;
    int n = i / VOC, v = i - n * VOC;
    embT[i] = f32_to_bf16_rne(embed[v * DEMB + n]);
}

__global__ __launch_bounds__(256) void gauss_embed_mfma_kernel(
    const int* __restrict__ text,            // [32, 256]
    const int* __restrict__ durs,            // [32, 256]
    const float* __restrict__ embed,         // [100, 384] fp32 (for pad rows)
    const unsigned short* __restrict__ embT, // [384, 100] bf16
    float* __restrict__ out,                 // [32, Tt, 384]
    int Tt)
{
    const int b   = blockIdx.y;
    const int t0  = blockIdx.x * TTILE;
    const int tid = threadIdx.x;
    const int wv   = tid >> 6;
    const int lane = tid & 63;
    const int nq   = lane & 15;   // n within 16-tile / m for A-frag
    const int q    = lane >> 4;   // quad

    __shared__ __align__(16) unsigned short s_embT[DEMB * VOC];  // 76800 B
    __shared__ __align__(16) unsigned short s_wp[TTILE * WPS];   // 6656 B
    __shared__ float s_scan[TC];
    __shared__ float s_part[256];
    __shared__ float s_invS[TTILE];
    __shared__ int   s_wtx[WIN];
    __shared__ int   s_j0, s_totdur;

    // ---- inclusive scan of durations (exact in fp32) ----
    s_scan[tid] = (float)durs[b * TC + tid];
    if (tid == 0) s_j0 = TC - 1;
    __syncthreads();
    for (int ofs = 1; ofs < TC; ofs <<= 1) {
        float v = (tid >= ofs) ? s_scan[tid - ofs] : 0.0f;
        __syncthreads();
        s_scan[tid] += v;
        __syncthreads();
    }

    // ---- covering char for t0; total duration ----
    {
        int en = (int)s_scan[tid];
        int st = tid ? (int)s_scan[tid - 1] : 0;
        if (t0 >= st && t0 < en) s_j0 = tid;   // unique (durs >= 1)
        if (tid == 0) s_totdur = (int)s_scan[TC - 1];
    }
    __syncthreads();

    int base = s_j0 - 31;
    base = base < 0 ? 0 : (base > TC - WIN ? TC - WIN : base);
    const int totdur = s_totdur;

    // ---- issue async staging of embT into LDS (75 x 1024B chunks) ----
    {
        const char* gsrc = (const char*)embT;
        for (int ch = wv; ch < 75; ch += 4) {
            __builtin_amdgcn_global_load_lds(
                (const __attribute__((address_space(1))) unsigned int*)(gsrc + ch * 1024 + lane * 16),
                (__attribute__((address_space(3))) unsigned int*)((char*)s_embT + ch * 1024),
                16, 0, 0);
        }
    }

    // ---- phase 1: W'[t][c] = bf16(w), fp32 row sums (overlaps staging) ----
    {
        const int t = tid & 31;       // frame within tile
        const int g = tid >> 5;       // char group 0..7, 12 chars each
        const float tf = (float)(t0 + t) + 0.5f;
        float lsum = 0.0f;
#pragma unroll
        for (int cc = 0; cc < 12; ++cc) {
            int c = g * 12 + cc;
            int j = base + c;
            float endf   = s_scan[j];
            float startf = j ? s_scan[j - 1] : 0.0f;
            float dur = endf - startf;
            float sig = dur * 0.5f + 1e-6f;          // dur/SIGMA_C + EPS
            float ctr = endf - dur * 0.5f;
            float z = (tf - ctr) / sig;
            float w = __expf(fmaf(-0.5f * z, z, -__logf(sig) - LOG_SQRT_2PI));
            lsum += w;
            s_wp[t * WPS + c] = f32_to_bf16_rne(w);
        }
        s_part[tid] = lsum;
        if (tid < WIN) s_wtx[tid] = text[b * TC + base + tid];
    }
    __syncthreads();   // drains staging too

    if (tid < TTILE) {
        float s = 1e-6f;
#pragma unroll
        for (int g = 0; g < 8; ++g) s += s_part[g * 32 + tid];
        s_invS[tid] = 1.0f / s;
    }
    __syncthreads();

    // ---- phase 2: D[32 x 384] = W'[32 x 96] x E[96 x 384] via MFMA ----
    // wave wv owns n columns [wv*96, wv*96+96) = 6 n-tiles of 16
    v4f acc[6][2];
#pragma unroll
    for (int nt = 0; nt < 6; ++nt)
#pragma unroll
        for (int mt = 0; mt < 2; ++mt) {
            v4f z = {0.0f, 0.0f, 0.0f, 0.0f};
            acc[nt][mt] = z;
        }

#pragma unroll
    for (int ks = 0; ks < 3; ++ks) {
        const int c0 = ks * 32;
        int vidx[8];
#pragma unroll
        for (int j = 0; j < 8; ++j) vidx[j] = s_wtx[c0 + q * 8 + j];
        // A-fragments: A[m=nq][k=q*8+j]  (W' rows t, k-contiguous b128)
        v8s a0 = *(const v8s*)(s_wp + nq * WPS + c0 + q * 8);
        v8s a1 = *(const v8s*)(s_wp + (16 + nq) * WPS + c0 + q * 8);
#pragma unroll
        for (int nt = 0; nt < 6; ++nt) {
            const unsigned short* col = s_embT + (wv * 96 + nt * 16 + nq) * VOC;
            v8s bf;
#pragma unroll
            for (int j = 0; j < 8; ++j) bf[j] = (short)col[vidx[j]];
            acc[nt][0] = __builtin_amdgcn_mfma_f32_16x16x32_bf16(a0, bf, acc[nt][0], 0, 0, 0);
            acc[nt][1] = __builtin_amdgcn_mfma_f32_16x16x32_bf16(a1, bf, acc[nt][1], 0, 0, 0);
        }
    }

    // ---- epilogue: normalize, pad rows -> embed[0], store ----
    float pe[6];
#pragma unroll
    for (int nt = 0; nt < 6; ++nt) pe[nt] = embed[wv * 96 + nt * 16 + nq]; // embed row 0 (PAD)

#pragma unroll
    for (int mt = 0; mt < 2; ++mt) {
#pragma unroll
        for (int r = 0; r < 4; ++r) {
            int tl = mt * 16 + q * 4 + r;   // C/D: row = q*4 + reg
            int t = t0 + tl;
            if (t >= Tt) continue;
            float sv = s_invS[tl];
            bool pad = (t >= totdur);
            float* orow = out + (size_t)(b * Tt + t) * DEMB + wv * 96 + nq;
#pragma unroll
            for (int nt = 0; nt < 6; ++nt) {
                float val = pad ? pe[nt] : acc[nt][mt][r] * sv;
                orow[nt * 16] = val;
            }
        }
    }
}

extern "C" void kernel_launch(void* const* d_in, const int* in_sizes, int n_in,
                              void* d_out, int out_size, void* d_ws, size_t ws_size,
                              hipStream_t stream) {
    const int*   text  = (const int*)d_in[0];
    const int*   durs  = (const int*)d_in[1];
    const float* embed = (const float*)d_in[2];
    float* out = (float*)d_out;

    const int B = 32;
    const int Tt = out_size / (B * DEMB);

    unsigned short* embT = (unsigned short*)d_ws;   // 76800 B
    embed_transpose_kernel<<<(DEMB * VOC + 255) / 256, 256, 0, stream>>>(embed, embT);

    dim3 grid((Tt + TTILE - 1) / TTILE, B);
    gauss_embed_mfma_kernel<<<grid, 256, 0, stream>>>(text, durs, embed, embT, out, Tt);
}

// Round 4
// 101.215 us; speedup vs baseline: 1.2393x; 1.0470x over previous
//
#include <hip/hip_runtime.h>

#define TC 256
#define DEMB 384
#define VOC 100
#define WIN 96
#define TTILE 32
#define WPS 104      // W' LDS row stride in bf16 elems (16B-aligned rows)
#define CST 288      // ET c-stride in elems (576 B rows; window offsets 16B-aligned)
#define LOG_SQRT_2PI 0.9189385332046727f

typedef short v8s __attribute__((ext_vector_type(8)));
typedef float v4f __attribute__((ext_vector_type(4)));

__device__ __forceinline__ unsigned short f32_to_bf16_rne(float f) {
    union { float f; unsigned int u; } x; x.f = f;
    unsigned int u = x.u;
    return (unsigned short)((u + 0x7FFFu + ((u >> 16) & 1u)) >> 16);
}

// Pre-pass: ET[b][n][c] = bf16(embed[text[b][c]][n]),  [32][384][288(c-stride)]
// Thread = (b, n-segment of 96, c). Reads coalesce via L1/L2 (embed is 150 KB,
// L2-resident); writes are 128 B contiguous per wave-inst (lane == c).
__global__ __launch_bounds__(256) void gather_transpose_kernel(
    const int* __restrict__ text, const float* __restrict__ embed,
    unsigned short* __restrict__ ET)
{
    int i = blockIdx.x * 256 + threadIdx.x;
    int c = i % CST;
    int r = i / CST;
    int nseg = r & 3;
    int b = r >> 2;
    if (c >= TC || b >= 32) return;
    int v = text[b * TC + c];
    const float* erow = embed + (size_t)v * DEMB + nseg * 96;
    unsigned short* dst = ET + ((size_t)b * DEMB + nseg * 96) * CST + c;
#pragma unroll
    for (int k = 0; k < 24; ++k) {
        float4 e = *(const float4*)(erow + 4 * k);
        dst[(4 * k + 0) * CST] = f32_to_bf16_rne(e.x);
        dst[(4 * k + 1) * CST] = f32_to_bf16_rne(e.y);
        dst[(4 * k + 2) * CST] = f32_to_bf16_rne(e.z);
        dst[(4 * k + 3) * CST] = f32_to_bf16_rne(e.w);
    }
}

__global__ __launch_bounds__(256, 4) void gauss_embed_mfma_kernel(
    const int* __restrict__ text,            // [32, 256]
    const int* __restrict__ durs,            // [32, 256]
    const float* __restrict__ embed,         // [100, 384] fp32 (pad rows)
    const unsigned short* __restrict__ ET,   // [32][384][CST] bf16 gathered
    float* __restrict__ out,                 // [32, Tt, 384]
    int Tt)
{
    const int b   = blockIdx.y;
    const int t0  = blockIdx.x * TTILE;
    const int tid = threadIdx.x;
    const int wv   = tid >> 6;    // wave 0..3: owns n columns [wv*96, wv*96+96)
    const int lane = tid & 63;
    const int nq   = lane & 15;   // n within 16-tile / m row for A-frag
    const int q    = lane >> 4;   // quad

    __shared__ float s_scan[TC];
    __shared__ float s_part[256];
    __shared__ __align__(16) unsigned short s_wp[TTILE * WPS];   // 6656 B
    __shared__ float s_invS[TTILE];
    __shared__ int   s_j0, s_totdur;

    // ---- inclusive scan of durations (exact in fp32: sums <= 2048) ----
    s_scan[tid] = (float)durs[b * TC + tid];
    if (tid == 0) s_j0 = TC - 1;
    __syncthreads();
    for (int ofs = 1; ofs < TC; ofs <<= 1) {
        float v = (tid >= ofs) ? s_scan[tid - ofs] : 0.0f;
        __syncthreads();
        s_scan[tid] += v;
        __syncthreads();
    }

    // ---- covering char for t0; total duration ----
    {
        int en = (int)s_scan[tid];
        int st = tid ? (int)s_scan[tid - 1] : 0;
        if (t0 >= st && t0 < en) s_j0 = tid;   // unique (durs >= 1)
        if (tid == 0) s_totdur = (int)s_scan[TC - 1];
    }
    __syncthreads();

    int base = s_j0 - 31;
    base = base < 0 ? 0 : base;
    base &= ~7;                                // 16B-align ET window reads
    base = base > TC - WIN ? TC - WIN : base;  // 160: multiple of 8
    const int totdur = s_totdur;

    // ---- phase 1: W'[t][c] = bf16(w), fp32 partial row sums ----
    {
        const int t = tid & 31;       // frame within tile
        const int g = tid >> 5;       // char group 0..7, 12 chars each
        const float tf = (float)(t0 + t) + 0.5f;
        float lsum = 0.0f;
#pragma unroll
        for (int cc = 0; cc < 12; ++cc) {
            int c = g * 12 + cc;
            int j = base + c;
            float endf   = s_scan[j];
            float startf = j ? s_scan[j - 1] : 0.0f;
            float dur = endf - startf;
            float sig = dur * 0.5f + 1e-6f;          // dur/SIGMA_C + EPS
            float ctr = endf - dur * 0.5f;
            float z = (tf - ctr) / sig;
            float w = __expf(fmaf(-0.5f * z, z, -__logf(sig) - LOG_SQRT_2PI));
            lsum += w;
            s_wp[t * WPS + c] = f32_to_bf16_rne(w);
        }
        s_part[tid] = lsum;
    }
    __syncthreads();

    if (tid < TTILE) {
        float s = 1e-6f;
#pragma unroll
        for (int g = 0; g < 8; ++g) s += s_part[g * 32 + tid];
        s_invS[tid] = 1.0f / s;
    }
    __syncthreads();

    // ---- phase 2: D[32 x 384] = W'[32 x 96] x E'[96 x 384] via MFMA ----
    const unsigned short* ETb = ET + (size_t)b * DEMB * CST;

    v4f acc[6][2];
#pragma unroll
    for (int nt = 0; nt < 6; ++nt)
#pragma unroll
        for (int mt = 0; mt < 2; ++mt) {
            v4f z = {0.0f, 0.0f, 0.0f, 0.0f};
            acc[nt][mt] = z;
        }

#pragma unroll
    for (int ks = 0; ks < 3; ++ks) {
        const int c0 = ks * 32 + q * 8;
        // A-frags: A[m=nq][k=q*8+j] from W' rows (16B-aligned b128)
        v8s a0 = *(const v8s*)(s_wp + nq * WPS + c0);
        v8s a1 = *(const v8s*)(s_wp + (16 + nq) * WPS + c0);
#pragma unroll
        for (int nt = 0; nt < 6; ++nt) {
            // B-frag: B[k=c][n=nq] = ET[n][base+c] — contiguous 16 B, aligned
            v8s bf = *(const v8s*)(ETb + (size_t)(wv * 96 + nt * 16 + nq) * CST + base + c0);
            acc[nt][0] = __builtin_amdgcn_mfma_f32_16x16x32_bf16(a0, bf, acc[nt][0], 0, 0, 0);
            acc[nt][1] = __builtin_amdgcn_mfma_f32_16x16x32_bf16(a1, bf, acc[nt][1], 0, 0, 0);
        }
    }

    // ---- epilogue: normalize, pad rows -> embed[0], store ----
    float pe[6];
#pragma unroll
    for (int nt = 0; nt < 6; ++nt) pe[nt] = embed[wv * 96 + nt * 16 + nq]; // row 0 (PAD)

#pragma unroll
    for (int mt = 0; mt < 2; ++mt) {
#pragma unroll
        for (int r = 0; r < 4; ++r) {
            int tl = mt * 16 + q * 4 + r;   // C/D: row = q*4 + reg
            int t = t0 + tl;
            if (t >= Tt) continue;
            float sv = s_invS[tl];
            bool pad = (t >= totdur);
            float* orow = out + (size_t)(b * Tt + t) * DEMB + wv * 96 + nq;
#pragma unroll
            for (int nt = 0; nt < 6; ++nt) {
                float val = pad ? pe[nt] : acc[nt][mt][r] * sv;
                orow[nt * 16] = val;
            }
        }
    }
}

extern "C" void kernel_launch(void* const* d_in, const int* in_sizes, int n_in,
                              void* d_out, int out_size, void* d_ws, size_t ws_size,
                              hipStream_t stream) {
    const int*   text  = (const int*)d_in[0];
    const int*   durs  = (const int*)d_in[1];
    const float* embed = (const float*)d_in[2];
    float* out = (float*)d_out;

    const int B = 32;
    const int Tt = out_size / (B * DEMB);

    unsigned short* ET = (unsigned short*)d_ws;   // 32*384*288*2 = 7.08 MB
    {
        int nthreads = 32 * 4 * CST;              // (b, nseg, c)
        gather_transpose_kernel<<<(nthreads + 255) / 256, 256, 0, stream>>>(text, embed, ET);
    }

    dim3 grid((Tt + TTILE - 1) / TTILE, B);
    gauss_embed_mfma_kernel<<<grid, 256, 0, stream>>>(text, durs, embed, ET, out, Tt);
}

// Round 5
// 100.457 us; speedup vs baseline: 1.2487x; 1.0075x over previous
//
#include <hip/hip_runtime.h>

#define TC 256
#define DEMB 384
#define VOC 100
#define WIN 96
#define TTILE 32
#define WPS 104      // W' LDS row stride in bf16 elems (16B-aligned rows)
#define CST 288      // ET c-stride in elems (576 B rows; 16B-aligned window reads)
#define LOG_SQRT_2PI 0.9189385332046727f

typedef short v8s __attribute__((ext_vector_type(8)));
typedef float v4f __attribute__((ext_vector_type(4)));

__device__ __forceinline__ unsigned short f32_to_bf16_rne(float f) {
    union { float f; unsigned int u; } x; x.f = f;
    unsigned int u = x.u;
    return (unsigned short)((u + 0x7FFFu + ((u >> 16) & 1u)) >> 16);
}

// Fused pre-pass.
// Blocks [0,576): ET[b][n][c] = bf16(embed[text[b][c]][n]); thread=(b,nseg16,c)
// Blocks [576,608): per-b scan of durs -> per-char params + per-tile j0 + totdur
__global__ __launch_bounds__(256) void prep_kernel(
    const int* __restrict__ text, const int* __restrict__ durs,
    const float* __restrict__ embed,
    unsigned short* __restrict__ ET,
    float* __restrict__ ctrA, float* __restrict__ isgA, float* __restrict__ lgA,
    int* __restrict__ j0A, int* __restrict__ totA)
{
    if (blockIdx.x < 576) {
        int i = blockIdx.x * 256 + threadIdx.x;
        int c = i % CST;
        int r = i / CST;            // b*16 + nseg
        int nseg = r & 15;
        int b = r >> 4;
        if (c >= TC) return;
        int v = text[b * TC + c];
        const float* erow = embed + (size_t)v * DEMB + nseg * 24;
        unsigned short* dst = ET + ((size_t)b * DEMB + nseg * 24) * CST + c;
#pragma unroll
        for (int k = 0; k < 6; ++k) {
            float4 e = *(const float4*)(erow + 4 * k);
            dst[(4 * k + 0) * CST] = f32_to_bf16_rne(e.x);
            dst[(4 * k + 1) * CST] = f32_to_bf16_rne(e.y);
            dst[(4 * k + 2) * CST] = f32_to_bf16_rne(e.z);
            dst[(4 * k + 3) * CST] = f32_to_bf16_rne(e.w);
        }
    } else {
        const int b = blockIdx.x - 576;
        const int c = threadIdx.x;
        const int lane = c & 63, wv = c >> 6;
        int d = durs[b * TC + c];
        // exact int inclusive scan: wave shuffle + LDS wave-sum combine
        int x = d;
#pragma unroll
        for (int ofs = 1; ofs < 64; ofs <<= 1) {
            int n = __shfl_up(x, ofs, 64);
            if (lane >= ofs) x += n;
        }
        __shared__ int s_wsum[4];
        if (lane == 63) s_wsum[wv] = x;
        __syncthreads();
        int pre = 0;
        for (int k = 0; k < wv; ++k) pre += s_wsum[k];
        int en = pre + x;
        int st = en - d;
        if (c == TC - 1) totA[b] = en;

        float df  = (float)d;
        float sig = df * 0.5f + 1e-6f;           // dur/SIGMA_C + EPS
        ctrA[b * TC + c] = (float)st + df * 0.5f;
        isgA[b * TC + c] = 1.0f / sig;
        lgA[b * TC + c]  = -logf(sig) - LOG_SQRT_2PI;

        // tiles whose first frame lies in [st, en): this char is j0
        for (int t0 = ((st + 31) >> 5) << 5; t0 < en; t0 += 32)
            j0A[b * 64 + (t0 >> 5)] = c;
    }
}

__global__ __launch_bounds__(256, 2) void gauss_embed_mfma_kernel(
    const float* __restrict__ embed,          // [100,384] fp32 (pad rows)
    const unsigned short* __restrict__ ET,    // [32][384][CST] bf16 gathered
    const float* __restrict__ ctrA, const float* __restrict__ isgA,
    const float* __restrict__ lgA,
    const int* __restrict__ j0A, const int* __restrict__ totA,
    float* __restrict__ out, int Tt)
{
    const int b   = blockIdx.y;
    const int t0  = blockIdx.x * TTILE;
    const int tid = threadIdx.x;
    const int totdur = totA[b];

    // ---- pure pad tile: every row = embed[0][:] ----
    if (t0 >= totdur) {
        const float4* e0 = (const float4*)embed;   // row 0 (PAD)
        int row = tid >> 3, q4 = tid & 7;
        int t = t0 + row;
        if (t < Tt) {
            float4* orow = (float4*)(out + (size_t)(b * Tt + t) * DEMB);
#pragma unroll
            for (int k = 0; k < 12; ++k) orow[q4 + 8 * k] = e0[q4 + 8 * k];
        }
        return;
    }

    const int wv   = tid >> 6;    // wave: n-cols [wv*96, wv*96+96)
    const int lane = tid & 63;
    const int nq   = lane & 15;
    const int q    = lane >> 4;

    __shared__ float s_ctr[WIN], s_isg[WIN], s_A[WIN];
    __shared__ __align__(16) unsigned short s_wp[TTILE * WPS];
    __shared__ float s_part[256];
    __shared__ float s_invS[TTILE];

    int j0 = j0A[b * 64 + (t0 >> 5)];
    int base = j0 - 31;
    base = base < 0 ? 0 : base;
    base &= ~7;                                // 16B-align ET window reads
    if (base > TC - WIN) base = TC - WIN;      // 160 (multiple of 8)

    if (tid < WIN) {
        s_ctr[tid] = ctrA[b * TC + base + tid];
        s_isg[tid] = isgA[b * TC + base + tid];
        s_A[tid]   = lgA[b * TC + base + tid];
    }
    __syncthreads();

    // ---- phase 1: W'[t][c] = bf16(w), partial row sums ----
    {
        const int t = tid & 31;
        const int g = tid >> 5;
        const float tf = (float)(t0 + t) + 0.5f;
        float lsum = 0.0f;
#pragma unroll
        for (int cc = 0; cc < 12; ++cc) {
            int c = g * 12 + cc;
            float z = (tf - s_ctr[c]) * s_isg[c];
            float w = __expf(fmaf(-0.5f * z, z, s_A[c]));
            lsum += w;
            s_wp[t * WPS + c] = f32_to_bf16_rne(w);
        }
        s_part[tid] = lsum;
    }
    __syncthreads();

    if (tid < TTILE) {
        float s = 1e-6f;
#pragma unroll
        for (int g = 0; g < 8; ++g) s += s_part[g * 32 + tid];
        s_invS[tid] = 1.0f / s;
    }
    __syncthreads();

    // ---- phase 2: D[32x384] = W'[32x96] x E'[96x384] via MFMA ----
    const unsigned short* ETb = ET + (size_t)b * DEMB * CST + base;

    v4f acc[6][2];
#pragma unroll
    for (int nt = 0; nt < 6; ++nt)
#pragma unroll
        for (int mt = 0; mt < 2; ++mt) {
            v4f z = {0.0f, 0.0f, 0.0f, 0.0f};
            acc[nt][mt] = z;
        }

#pragma unroll
    for (int ks = 0; ks < 3; ++ks) {
        const int c0 = ks * 32 + q * 8;
        v8s a0 = *(const v8s*)(s_wp + nq * WPS + c0);
        v8s a1 = *(const v8s*)(s_wp + (16 + nq) * WPS + c0);
#pragma unroll
        for (int nt = 0; nt < 6; ++nt) {
            v8s bf = *(const v8s*)(ETb + (size_t)(wv * 96 + nt * 16 + nq) * CST + c0);
            acc[nt][0] = __builtin_amdgcn_mfma_f32_16x16x32_bf16(a0, bf, acc[nt][0], 0, 0, 0);
            acc[nt][1] = __builtin_amdgcn_mfma_f32_16x16x32_bf16(a1, bf, acc[nt][1], 0, 0, 0);
        }
    }

    // ---- epilogue: normalize, pad rows -> embed[0], store ----
    const bool anypad = (t0 + TTILE > totdur);   // wave-uniform
    float pe[6];
    if (anypad) {
#pragma unroll
        for (int nt = 0; nt < 6; ++nt) pe[nt] = embed[wv * 96 + nt * 16 + nq];
    }

#pragma unroll
    for (int mt = 0; mt < 2; ++mt) {
#pragma unroll
        for (int r = 0; r < 4; ++r) {
            int tl = mt * 16 + q * 4 + r;        // C/D: row = q*4 + reg
            int t = t0 + tl;
            if (t >= Tt) continue;
            float sv = s_invS[tl];
            bool pad = anypad && (t >= totdur);
            float* orow = out + (size_t)(b * Tt + t) * DEMB + wv * 96 + nq;
#pragma unroll
            for (int nt = 0; nt < 6; ++nt) {
                float val = pad ? pe[nt] : acc[nt][mt][r] * sv;
                orow[nt * 16] = val;
            }
        }
    }
}

extern "C" void kernel_launch(void* const* d_in, const int* in_sizes, int n_in,
                              void* d_out, int out_size, void* d_ws, size_t ws_size,
                              hipStream_t stream) {
    const int*   text  = (const int*)d_in[0];
    const int*   durs  = (const int*)d_in[1];
    const float* embed = (const float*)d_in[2];
    float* out = (float*)d_out;

    const int B = 32;
    const int Tt = out_size / (B * DEMB);

    // workspace layout
    char* ws = (char*)d_ws;
    unsigned short* ET = (unsigned short*)ws;                   // 7,077,888 B
    float* ctrA = (float*)(ws + 7077888);                       // 32,768 B
    float* isgA = (float*)(ws + 7077888 + 32768);               // 32,768 B
    float* lgA  = (float*)(ws + 7077888 + 65536);               // 32,768 B
    int*   j0A  = (int*)  (ws + 7077888 + 98304);               // 8,192 B
    int*   totA = (int*)  (ws + 7077888 + 106496);              // 128 B

    prep_kernel<<<608, 256, 0, stream>>>(text, durs, embed, ET,
                                         ctrA, isgA, lgA, j0A, totA);

    dim3 grid((Tt + TTILE - 1) / TTILE, B);
    gauss_embed_mfma_kernel<<<grid, 256, 0, stream>>>(embed, ET, ctrA, isgA, lgA,
                                                      j0A, totA, out, Tt);
}